// Round 1
// baseline (205.153 us; speedup 1.0000x reference)
//
#include <hip/hip_runtime.h>
#include <hip/hip_bf16.h>

#define DEV __device__ __forceinline__

typedef unsigned short u16;
typedef __attribute__((ext_vector_type(8))) short bf16x8;
typedef __attribute__((ext_vector_type(4))) float f32x4;
typedef __attribute__((ext_vector_type(4))) unsigned short us4;

DEV void gld_lds16(const void* g, void* l) {
  __builtin_amdgcn_global_load_lds((const __attribute__((address_space(1))) void*)g,
                                   (__attribute__((address_space(3))) void*)l, 16, 0, 0);
}

DEV u16 f2bf(float x) {  // RNE f32->bf16 (inputs finite)
  union { float f; unsigned u; } v; v.f = x;
  unsigned r = v.u + 0x7FFFu + ((v.u >> 16) & 1u);
  return (u16)(r >> 16);
}

// ---------------- prep: cast x to bf16 ----------------
__global__ __launch_bounds__(256) void k_cast_x(const float* __restrict__ x, u16* __restrict__ xb) {
  int i = (blockIdx.x * 256 + threadIdx.x) * 4;
  const float4 v = *(const float4*)(x + i);
  us4 o; o.x = f2bf(v.x); o.y = f2bf(v.y); o.z = f2bf(v.z); o.w = f2bf(v.w);
  *(us4*)(xb + i) = o;
}

// ---------------- prep: transpose-pack weights to bf16 ----------------
// Wq/Wk/Wv: [H][1024][64] -> Wt[j=(h*64+d)][m] ; Wo: [1024][1024] -> Wot[n][m]
__global__ __launch_bounds__(256) void k_prep_w(const float* __restrict__ Wq, const float* __restrict__ Wk,
                                                const float* __restrict__ Wv, const float* __restrict__ Wo,
                                                u16* __restrict__ wqkt, u16* __restrict__ wvt,
                                                u16* __restrict__ wot) {
  __shared__ float t[64][65];
  const int bb = blockIdx.x, tid = threadIdx.x;
  const float* src; u16* dst; int src_ld, dst_row0, dst_col0;
  if (bb < 768) {
    int which = bb >> 8, h = (bb >> 4) & 15, m0 = (bb & 15) * 64;
    const float* W = which == 0 ? Wq : (which == 1 ? Wk : Wv);
    src = W + h * 65536 + m0 * 64; src_ld = 64;
    dst = (which == 2) ? wvt : (wqkt + (which == 1 ? (1024 * 1024) : 0));
    dst_row0 = h * 64; dst_col0 = m0;
  } else {
    int t2 = bb - 768, mt = t2 >> 4, nt = t2 & 15;
    src = Wo + (size_t)(mt * 64) * 1024 + nt * 64; src_ld = 1024;
    dst = wot; dst_row0 = nt * 64; dst_col0 = mt * 64;
  }
  {
    int r = tid >> 2, c0 = (tid & 3) * 16;
    const float* s = src + (size_t)r * src_ld + c0;
#pragma unroll
    for (int q = 0; q < 4; ++q) {
      float4 v = *(const float4*)(s + q * 4);
      t[r][c0 + q * 4 + 0] = v.x; t[r][c0 + q * 4 + 1] = v.y;
      t[r][c0 + q * 4 + 2] = v.z; t[r][c0 + q * 4 + 3] = v.w;
    }
  }
  __syncthreads();
  {
    int d = tid >> 2, mb = (tid & 3) * 16;
    bf16x8 v0, v1;
#pragma unroll
    for (int e = 0; e < 8; ++e) {
      v0[e] = (short)f2bf(t[mb + e][d]);
      v1[e] = (short)f2bf(t[mb + 8 + e][d]);
    }
    u16* dp = dst + (size_t)(dst_row0 + d) * 1024 + dst_col0 + mb;
    *(bf16x8*)(dp) = v0;
    *(bf16x8*)(dp + 8) = v1;
  }
}

// ---------------- GEMM: C[M,N] = A[M,K] x Bt[N,K]^T (+bias, epilogue by MODE) ----------------
// MODE 0: A=x[4096,1024], Bt=wqkt[2048,1024]; out bf16 qk[4096,2048]; bias bq/bk by col; Q cols scaled 0.125
// MODE 1: A=wvt[1024,1024], Bt=x[4096,1024]; out bf16 vt[(b*16+h)*64+d][2048]; bias bv by row
// MODE 2: A=attn_out[4096,1024], Bt=wot[1024,1024]; out f32 d_out[4096,1024]; bias bo by col
template <int MODE>
__global__ __launch_bounds__(256) void k_gemm(const u16* __restrict__ A, const u16* __restrict__ Bt,
                                              const float* __restrict__ b0, const float* __restrict__ b1,
                                              u16* __restrict__ outb, float* __restrict__ outf) {
  constexpr int K = 1024;
  __shared__ __align__(16) u16 As[128 * 64];
  __shared__ __align__(16) u16 Bs[128 * 64];
  const int tid = threadIdx.x, wid = tid >> 6, lane = tid & 63;
  const int lo = lane & 15, hi = lane >> 4;
  const int wr = wid >> 1, wc = wid & 1;
  const int bm = blockIdx.y, bn = blockIdx.x;
  const u16* Ab = A + (size_t)bm * 128 * K;
  const u16* Bb = Bt + (size_t)bn * 128 * K;
  const int sr = lane >> 3, sc = lane & 7;
  f32x4 acc[4][4] = {};
  for (int k0 = 0; k0 < K; k0 += 64) {
    __syncthreads();  // prior reads done before restage
#pragma unroll
    for (int i = 0; i < 4; ++i) {
      int r = wid * 32 + i * 8 + sr;
      int cs = sc ^ (r & 7);  // pre-swizzled source -> linear LDS dest == swizzled content
      gld_lds16(Ab + (size_t)r * K + k0 + cs * 8, As + (wid * 32 + i * 8) * 64);
      gld_lds16(Bb + (size_t)r * K + k0 + cs * 8, Bs + (wid * 32 + i * 8) * 64);
    }
    __syncthreads();  // vmcnt(0) drain: tile ready
#pragma unroll
    for (int ks = 0; ks < 2; ++ks) {
      bf16x8 af[4], bfr[4];
#pragma unroll
      for (int mt = 0; mt < 4; ++mt) {
        int r = wr * 64 + mt * 16 + lo;
        int c = (hi + 4 * ks) ^ (r & 7);
        af[mt] = *(const bf16x8*)(As + r * 64 + c * 8);
      }
#pragma unroll
      for (int nt = 0; nt < 4; ++nt) {
        int r = wc * 64 + nt * 16 + lo;
        int c = (hi + 4 * ks) ^ (r & 7);
        bfr[nt] = *(const bf16x8*)(Bs + r * 64 + c * 8);
      }
#pragma unroll
      for (int mt = 0; mt < 4; ++mt)
#pragma unroll
        for (int nt = 0; nt < 4; ++nt)
          acc[mt][nt] = __builtin_amdgcn_mfma_f32_16x16x32_bf16(af[mt], bfr[nt], acc[mt][nt], 0, 0, 0);
    }
  }
#pragma unroll
  for (int mt = 0; mt < 4; ++mt) {
#pragma unroll
    for (int nt = 0; nt < 4; ++nt) {
      const int i0 = bm * 128 + wr * 64 + mt * 16 + hi * 4;
      const int j = bn * 128 + wc * 64 + nt * 16 + lo;
#pragma unroll
      for (int rg = 0; rg < 4; ++rg) {
        const int i = i0 + rg;
        float v = acc[mt][nt][rg];
        if (MODE == 0) {
          v += (j < 1024) ? b0[j] : b1[j - 1024];
          if (j < 1024) v *= 0.125f;  // fold 1/sqrt(D) into Q (exact in bf16)
          outb[(size_t)i * 2048 + j] = f2bf(v);
        } else if (MODE == 1) {
          v += b0[i];
          outb[(size_t)((j >> 11) * 1024 + i) * 2048 + (j & 2047)] = f2bf(v);
        } else {
          v += b0[j];
          outf[(size_t)i * 1024 + j] = v;
        }
      }
    }
  }
}

// ---------------- flash attention ----------------
// qk: [4096][2048] bf16 (Q cols 0..1023 pre-scaled, K cols 1024..2047)
// vt: [(b*16+h)*64 + d][2048] bf16 (V transposed)
// ao: [4096][1024] bf16 concat output
__global__ __launch_bounds__(256) void k_attn(const u16* __restrict__ qk, const u16* __restrict__ vt,
                                              u16* __restrict__ ao) {
  __shared__ __align__(16) u16 Kl[2][64 * 64];
  __shared__ __align__(16) u16 Vl[2][64 * 64];
  __shared__ __align__(16) u16 Pl[4][16 * 72];
  const int tid = threadIdx.x, wid = tid >> 6, lane = tid & 63;
  const int lo = lane & 15, hi = lane >> 4;
  const int bxi = blockIdx.x;
  const int qt = bxi & 31, bh = bxi >> 5;
  const int b = bh >> 4, h = bh & 15;

  // Q fragments held in registers for the whole block
  const size_t qrow = (size_t)(b * 2048 + qt * 64 + wid * 16 + lo);
  bf16x8 aq[2];
  aq[0] = *(const bf16x8*)(qk + qrow * 2048 + h * 64 + hi * 8);
  aq[1] = *(const bf16x8*)(qk + qrow * 2048 + h * 64 + 32 + hi * 8);

  const u16* Kg = qk + 1024 + (size_t)b * 2048 * 2048 + h * 64;  // + t*2048
  const u16* Vg = vt + (size_t)bh * 64 * 2048;                   // + d*2048 + t
  const int sr = lane >> 3, sc = lane & 7;

  f32x4 acco[4] = {};
  float m_run[4], l_run[4];
#pragma unroll
  for (int r = 0; r < 4; ++r) { m_run[r] = -1e30f; l_run[r] = 0.f; }

  // stage tile 0
#pragma unroll
  for (int i = 0; i < 2; ++i) {
    int r = wid * 16 + i * 8 + sr;
    int cs = sc ^ (r & 7);
    gld_lds16(Kg + (size_t)r * 2048 + cs * 8, Kl[0] + (wid * 16 + i * 8) * 64);
    gld_lds16(Vg + (size_t)r * 2048 + cs * 8, Vl[0] + (wid * 16 + i * 8) * 64);
  }

  for (int it = 0; it < 32; ++it) {
    __syncthreads();  // drains vmcnt: tile `it` ready; also separates prior reads from next stage
    if (it + 1 < 32) {
      const int t0 = (it + 1) * 64, bufn = (it + 1) & 1;
#pragma unroll
      for (int i = 0; i < 2; ++i) {
        int r = wid * 16 + i * 8 + sr;
        int cs = sc ^ (r & 7);
        gld_lds16(Kg + (size_t)(t0 + r) * 2048 + cs * 8, Kl[bufn] + (wid * 16 + i * 8) * 64);
        gld_lds16(Vg + (size_t)r * 2048 + t0 + cs * 8, Vl[bufn] + (wid * 16 + i * 8) * 64);
      }
    }
    const u16* Kb = Kl[it & 1];
    const u16* Vb = Vl[it & 1];

    // S = Q K^T : rows q (this wave's 16), cols t (64)
    f32x4 accs[4] = {};
#pragma unroll
    for (int ks = 0; ks < 2; ++ks)
#pragma unroll
      for (int nt = 0; nt < 4; ++nt) {
        int r = nt * 16 + lo;
        int c = (hi + 4 * ks) ^ (r & 7);
        bf16x8 bk = *(const bf16x8*)(Kb + r * 64 + c * 8);
        accs[nt] = __builtin_amdgcn_mfma_f32_16x16x32_bf16(aq[ks], bk, accs[nt], 0, 0, 0);
      }

    // online softmax; C-layout: value (nt,rg) at row q=hi*4+rg, col t=lo+16*nt
    float p[4][4];
#pragma unroll
    for (int rg = 0; rg < 4; ++rg) {
      float mx = fmaxf(fmaxf(accs[0][rg], accs[1][rg]), fmaxf(accs[2][rg], accs[3][rg]));
      mx = fmaxf(mx, __shfl_xor(mx, 1, 16));
      mx = fmaxf(mx, __shfl_xor(mx, 2, 16));
      mx = fmaxf(mx, __shfl_xor(mx, 4, 16));
      mx = fmaxf(mx, __shfl_xor(mx, 8, 16));
      float mn = fmaxf(m_run[rg], mx);
      float al = __expf(m_run[rg] - mn);
      float rs = 0.f;
#pragma unroll
      for (int nt = 0; nt < 4; ++nt) {
        float e = __expf(accs[nt][rg] - mn);
        p[nt][rg] = e; rs += e;
      }
      rs += __shfl_xor(rs, 1, 16);
      rs += __shfl_xor(rs, 2, 16);
      rs += __shfl_xor(rs, 4, 16);
      rs += __shfl_xor(rs, 8, 16);
      l_run[rg] = l_run[rg] * al + rs;
      m_run[rg] = mn;
#pragma unroll
      for (int dt = 0; dt < 4; ++dt) acco[dt][rg] *= al;
    }

    // P -> per-wave LDS [16 rows q][72 pitch], cols t
#pragma unroll
    for (int nt = 0; nt < 4; ++nt)
#pragma unroll
      for (int rg = 0; rg < 4; ++rg)
        Pl[wid][(hi * 4 + rg) * 72 + nt * 16 + lo] = f2bf(p[nt][rg]);
    asm volatile("s_waitcnt lgkmcnt(0)" ::: "memory");

    // O += P * V  (A = P rows q, B = V^T rows d -> B[k=t][n=d])
#pragma unroll
    for (int ks = 0; ks < 2; ++ks) {
      bf16x8 pa = *(const bf16x8*)(Pl[wid] + lo * 72 + ks * 32 + hi * 8);
#pragma unroll
      for (int dt = 0; dt < 4; ++dt) {
        int r = dt * 16 + lo;
        int c = (hi + 4 * ks) ^ (r & 7);
        bf16x8 bv = *(const bf16x8*)(Vb + r * 64 + c * 8);
        acco[dt] = __builtin_amdgcn_mfma_f32_16x16x32_bf16(pa, bv, acco[dt], 0, 0, 0);
      }
    }
  }

#pragma unroll
  for (int rg = 0; rg < 4; ++rg) l_run[rg] = 1.f / l_run[rg];
  const int q0 = qt * 64 + wid * 16 + hi * 4;
#pragma unroll
  for (int dt = 0; dt < 4; ++dt)
#pragma unroll
    for (int rg = 0; rg < 4; ++rg) {
      float o = acco[dt][rg] * l_run[rg];
      ao[(size_t)(b * 2048 + q0 + rg) * 1024 + h * 64 + dt * 16 + lo] = f2bf(o);
    }
}

// ---------------- launch ----------------
extern "C" void kernel_launch(void* const* d_in, const int* in_sizes, int n_in,
                              void* d_out, int out_size, void* d_ws, size_t ws_size,
                              hipStream_t stream) {
  const float* x  = (const float*)d_in[0];
  const float* Wq = (const float*)d_in[1];
  const float* bq = (const float*)d_in[2];
  const float* Wk = (const float*)d_in[3];
  const float* bk = (const float*)d_in[4];
  const float* Wv = (const float*)d_in[5];
  const float* bv = (const float*)d_in[6];
  const float* Wo = (const float*)d_in[7];
  const float* bo = (const float*)d_in[8];
  float* out = (float*)d_out;

  char* ws = (char*)d_ws;
  u16* xb   = (u16*)(ws);                        // 8 MB  x bf16 [4096][1024]
  u16* wqkt = (u16*)(ws + (8u << 20));           // 4 MB  [2048][1024]
  u16* wvt  = (u16*)(ws + (12u << 20));          // 2 MB  [1024][1024]
  u16* wot  = (u16*)(ws + (14u << 20));          // 2 MB  [1024][1024]
  u16* qk   = (u16*)(ws + (16u << 20));          // 16 MB [4096][2048]
  u16* vt   = (u16*)(ws + (32u << 20));          // 8 MB  [2*16*64][2048]
  u16* aob  = (u16*)(ws + (40u << 20));          // 8 MB  [4096][1024]   (48 MB total)

  k_cast_x<<<4096, 256, 0, stream>>>(x, xb);
  k_prep_w<<<1024, 256, 0, stream>>>(Wq, Wk, Wv, Wo, wqkt, wvt, wot);
  k_gemm<0><<<dim3(16, 32), 256, 0, stream>>>(xb, wqkt, bq, bk, qk, nullptr);
  k_gemm<1><<<dim3(32, 8), 256, 0, stream>>>(wvt, xb, bv, nullptr, vt, nullptr);
  k_attn<<<1024, 256, 0, stream>>>(qk, vt, aob);
  k_gemm<2><<<dim3(8, 32), 256, 0, stream>>>(aob, wot, bo, nullptr, nullptr, out);
}

// Round 2
// 147.585 us; speedup vs baseline: 1.3901x; 1.3901x over previous
//
#include <hip/hip_runtime.h>
#include <hip/hip_bf16.h>

#define DEV __device__ __forceinline__

typedef unsigned short u16;
typedef __attribute__((ext_vector_type(8))) short bf16x8;
typedef __attribute__((ext_vector_type(4))) float f32x4;
typedef __attribute__((ext_vector_type(4))) unsigned short us4;

DEV void gld_lds16(const void* g, void* l) {
  __builtin_amdgcn_global_load_lds((const __attribute__((address_space(1))) void*)g,
                                   (__attribute__((address_space(3))) void*)l, 16, 0, 0);
}

DEV u16 f2bf(float x) {  // RNE f32->bf16 (inputs finite)
  union { float f; unsigned u; } v; v.f = x;
  unsigned r = v.u + 0x7FFFu + ((v.u >> 16) & 1u);
  return (u16)(r >> 16);
}

DEV float ex2(float x) {  // 2^x
  float r; asm("v_exp_f32 %0, %1" : "=v"(r) : "v"(x)); return r;
}

DEV unsigned cvtpk(float a, float b) {  // [bf16(b)<<16 | bf16(a)]
  unsigned r; asm("v_cvt_pk_bf16_f32 %0, %1, %2" : "=v"(r) : "v"(a), "v"(b)); return r;
}

// ---------------- prep: cast x to bf16 ----------------
__global__ __launch_bounds__(256) void k_cast_x(const float* __restrict__ x, u16* __restrict__ xb) {
  int i = (blockIdx.x * 256 + threadIdx.x) * 4;
  const float4 v = *(const float4*)(x + i);
  us4 o; o.x = f2bf(v.x); o.y = f2bf(v.y); o.z = f2bf(v.z); o.w = f2bf(v.w);
  *(us4*)(xb + i) = o;
}

// ---------------- prep: transpose-pack weights to bf16 ----------------
__global__ __launch_bounds__(256) void k_prep_w(const float* __restrict__ Wq, const float* __restrict__ Wk,
                                                const float* __restrict__ Wv, const float* __restrict__ Wo,
                                                u16* __restrict__ wqkt, u16* __restrict__ wvt,
                                                u16* __restrict__ wot) {
  __shared__ float t[64][65];
  const int bb = blockIdx.x, tid = threadIdx.x;
  const float* src; u16* dst; int src_ld, dst_row0, dst_col0;
  if (bb < 768) {
    int which = bb >> 8, h = (bb >> 4) & 15, m0 = (bb & 15) * 64;
    const float* W = which == 0 ? Wq : (which == 1 ? Wk : Wv);
    src = W + h * 65536 + m0 * 64; src_ld = 64;
    dst = (which == 2) ? wvt : (wqkt + (which == 1 ? (1024 * 1024) : 0));
    dst_row0 = h * 64; dst_col0 = m0;
  } else {
    int t2 = bb - 768, mt = t2 >> 4, nt = t2 & 15;
    src = Wo + (size_t)(mt * 64) * 1024 + nt * 64; src_ld = 1024;
    dst = wot; dst_row0 = nt * 64; dst_col0 = mt * 64;
  }
  {
    int r = tid >> 2, c0 = (tid & 3) * 16;
    const float* s = src + (size_t)r * src_ld + c0;
#pragma unroll
    for (int q = 0; q < 4; ++q) {
      float4 v = *(const float4*)(s + q * 4);
      t[r][c0 + q * 4 + 0] = v.x; t[r][c0 + q * 4 + 1] = v.y;
      t[r][c0 + q * 4 + 2] = v.z; t[r][c0 + q * 4 + 3] = v.w;
    }
  }
  __syncthreads();
  {
    int d = tid >> 2, mb = (tid & 3) * 16;
    bf16x8 v0, v1;
#pragma unroll
    for (int e = 0; e < 8; ++e) {
      v0[e] = (short)f2bf(t[mb + e][d]);
      v1[e] = (short)f2bf(t[mb + 8 + e][d]);
    }
    u16* dp = dst + (size_t)(dst_row0 + d) * 1024 + dst_col0 + mb;
    *(bf16x8*)(dp) = v0;
    *(bf16x8*)(dp + 8) = v1;
  }
}

// ---------------- GEMM: C[M,N] = A[M,K] x Bt[N,K]^T (+bias, epilogue by MODE) ----------------
// MODE 0: out bf16 qk[4096,2048]; Q cols scaled by 0.125*log2(e) (exp2-domain softmax)
// MODE 1: out bf16 vt[(b*16+h)*64+d][2048]
// MODE 2: out f32 d_out[4096,1024]
template <int MODE>
__global__ __launch_bounds__(256) void k_gemm(const u16* __restrict__ A, const u16* __restrict__ Bt,
                                              const float* __restrict__ b0, const float* __restrict__ b1,
                                              u16* __restrict__ outb, float* __restrict__ outf) {
  constexpr int K = 1024;
  __shared__ __align__(16) u16 As[128 * 64];
  __shared__ __align__(16) u16 Bs[128 * 64];
  const int tid = threadIdx.x, wid = tid >> 6, lane = tid & 63;
  const int lo = lane & 15, hi = lane >> 4;
  const int wr = wid >> 1, wc = wid & 1;
  const int bm = blockIdx.y, bn = blockIdx.x;
  const u16* Ab = A + (size_t)bm * 128 * K;
  const u16* Bb = Bt + (size_t)bn * 128 * K;
  const int sr = lane >> 3, sc = lane & 7;
  f32x4 acc[4][4] = {};
  for (int k0 = 0; k0 < K; k0 += 64) {
    __syncthreads();
#pragma unroll
    for (int i = 0; i < 4; ++i) {
      int r = wid * 32 + i * 8 + sr;
      int cs = sc ^ (r & 7);
      gld_lds16(Ab + (size_t)r * K + k0 + cs * 8, As + (wid * 32 + i * 8) * 64);
      gld_lds16(Bb + (size_t)r * K + k0 + cs * 8, Bs + (wid * 32 + i * 8) * 64);
    }
    __syncthreads();
#pragma unroll
    for (int ks = 0; ks < 2; ++ks) {
      bf16x8 af[4], bfr[4];
#pragma unroll
      for (int mt = 0; mt < 4; ++mt) {
        int r = wr * 64 + mt * 16 + lo;
        int c = (hi + 4 * ks) ^ (r & 7);
        af[mt] = *(const bf16x8*)(As + r * 64 + c * 8);
      }
#pragma unroll
      for (int nt = 0; nt < 4; ++nt) {
        int r = wc * 64 + nt * 16 + lo;
        int c = (hi + 4 * ks) ^ (r & 7);
        bfr[nt] = *(const bf16x8*)(Bs + r * 64 + c * 8);
      }
#pragma unroll
      for (int mt = 0; mt < 4; ++mt)
#pragma unroll
        for (int nt = 0; nt < 4; ++nt)
          acc[mt][nt] = __builtin_amdgcn_mfma_f32_16x16x32_bf16(af[mt], bfr[nt], acc[mt][nt], 0, 0, 0);
    }
  }
#pragma unroll
  for (int mt = 0; mt < 4; ++mt) {
#pragma unroll
    for (int nt = 0; nt < 4; ++nt) {
      const int i0 = bm * 128 + wr * 64 + mt * 16 + hi * 4;
      const int j = bn * 128 + wc * 64 + nt * 16 + lo;
#pragma unroll
      for (int rg = 0; rg < 4; ++rg) {
        const int i = i0 + rg;
        float v = acc[mt][nt][rg];
        if (MODE == 0) {
          v += (j < 1024) ? b0[j] : b1[j - 1024];
          if (j < 1024) v *= 0.18033688011112042f;  // (1/8)*log2(e): exp2-domain logits
          outb[(size_t)i * 2048 + j] = f2bf(v);
        } else if (MODE == 1) {
          v += b0[i];
          outb[(size_t)((j >> 11) * 1024 + i) * 2048 + (j & 2047)] = f2bf(v);
        } else {
          v += b0[j];
          outf[(size_t)i * 1024 + j] = v;
        }
      }
    }
  }
}

// ---------------- flash attention (swapped QK^T: lane-local softmax rows) ----------------
// qk: [4096][2048] bf16 (Q cols pre-scaled by (1/8)log2e, K cols 1024..2047)
// vt: [(b*16+h)*64 + d][2048] bf16 (V transposed)
// ao: [4096][1024] bf16 concat output
// Block: 4 waves x 32 q-rows = 128 q. Wave computes S^T = mfma(K, Q): lane owns
// q = qtile*16 + (lane&15); 16 t-values in-register per qtile -> lane-local max/sum
// + 2 shuffles. P routed via per-wave LDS [q][t] pitch 72 (packed b64 writes).
__global__ __launch_bounds__(256) void k_attn(const u16* __restrict__ qk, const u16* __restrict__ vt,
                                              u16* __restrict__ ao) {
  __shared__ __align__(16) u16 Kl[2][64 * 64];
  __shared__ __align__(16) u16 Vl[2][64 * 64];
  __shared__ __align__(16) u16 Pl[4][2][16 * 72];
  const int tid = threadIdx.x, wid = tid >> 6, lane = tid & 63;
  const int lo = lane & 15, hi = lane >> 4;
  const int qb = blockIdx.x & 15, bh = blockIdx.x >> 4;
  const int b = bh >> 4, h = bh & 15;
  const int qbase = qb * 128 + wid * 32;

  // Q as B-fragments (lane: n=q=lo, k=d=hi*8+e), held for the whole block
  bf16x8 qB[2][2];
#pragma unroll
  for (int qt = 0; qt < 2; ++qt)
#pragma unroll
    for (int ks = 0; ks < 2; ++ks)
      qB[qt][ks] = *(const bf16x8*)(qk + (size_t)(b * 2048 + qbase + qt * 16 + lo) * 2048 +
                                    h * 64 + ks * 32 + hi * 8);

  const u16* Kg = qk + 1024 + (size_t)b * 2048 * 2048 + h * 64;  // + t*2048
  const u16* Vg = vt + (size_t)bh * 64 * 2048;                   // + d*2048 + t
  const int sr = lane >> 3, sc = lane & 7;

  f32x4 acco[2][4] = {};
  float m_run[2] = {-1e30f, -1e30f}, l_run[2] = {0.f, 0.f};

  // stage tile 0
#pragma unroll
  for (int i = 0; i < 2; ++i) {
    int r = wid * 16 + i * 8 + sr;
    int cs = sc ^ (r & 7);
    gld_lds16(Kg + (size_t)r * 2048 + cs * 8, Kl[0] + (wid * 16 + i * 8) * 64);
    gld_lds16(Vg + (size_t)r * 2048 + cs * 8, Vl[0] + (wid * 16 + i * 8) * 64);
  }

  for (int it = 0; it < 32; ++it) {
    __syncthreads();  // tile `it` staged (vmcnt drained at each wave's barrier entry)
    if (it + 1 < 32) {
      const int t0 = (it + 1) * 64, bufn = (it + 1) & 1;
#pragma unroll
      for (int i = 0; i < 2; ++i) {
        int r = wid * 16 + i * 8 + sr;
        int cs = sc ^ (r & 7);
        gld_lds16(Kg + (size_t)(t0 + r) * 2048 + cs * 8, Kl[bufn] + (wid * 16 + i * 8) * 64);
        gld_lds16(Vg + (size_t)r * 2048 + t0 + cs * 8, Vl[bufn] + (wid * 16 + i * 8) * 64);
      }
    }
    const u16* Kb = Kl[it & 1];
    const u16* Vb = Vl[it & 1];

    // S^T = K * Q^T : C[m=t][n=q]; lane holds 16 t-values for q=qtile*16+lo
    f32x4 accs[2][4] = {};
#pragma unroll
    for (int ks = 0; ks < 2; ++ks)
#pragma unroll
      for (int mt = 0; mt < 4; ++mt) {
        int r = mt * 16 + lo;
        int c = (hi + 4 * ks) ^ (r & 7);
        bf16x8 ka = *(const bf16x8*)(Kb + r * 64 + c * 8);
        accs[0][mt] = __builtin_amdgcn_mfma_f32_16x16x32_bf16(ka, qB[0][ks], accs[0][mt], 0, 0, 0);
        accs[1][mt] = __builtin_amdgcn_mfma_f32_16x16x32_bf16(ka, qB[1][ks], accs[1][mt], 0, 0, 0);
      }

    // lane-local online softmax (exp2 domain), defer-max THR=8
#pragma unroll
    for (int qt = 0; qt < 2; ++qt) {
      float mx = accs[qt][0][0];
#pragma unroll
      for (int mt = 0; mt < 4; ++mt)
#pragma unroll
        for (int rg = 0; rg < 4; ++rg) mx = fmaxf(mx, accs[qt][mt][rg]);
      mx = fmaxf(mx, __shfl_xor(mx, 16));
      mx = fmaxf(mx, __shfl_xor(mx, 32));
      if (mx > m_run[qt] + 8.f) {  // rescale only on significant max growth
        float al = ex2(m_run[qt] - mx);
        m_run[qt] = mx;
        l_run[qt] *= al;
#pragma unroll
        for (int dt = 0; dt < 4; ++dt) acco[qt][dt] *= al;
      }
      float rs = 0.f;
      u16* Pw = Pl[wid][qt];
#pragma unroll
      for (int mt = 0; mt < 4; ++mt) {  // t = mt*16 + hi*4 + rg
        float p0 = ex2(accs[qt][mt][0] - m_run[qt]);
        float p1 = ex2(accs[qt][mt][1] - m_run[qt]);
        float p2 = ex2(accs[qt][mt][2] - m_run[qt]);
        float p3 = ex2(accs[qt][mt][3] - m_run[qt]);
        rs += (p0 + p1) + (p2 + p3);
        uint2 w; w.x = cvtpk(p0, p1); w.y = cvtpk(p2, p3);
        *(uint2*)(Pw + lo * 72 + mt * 16 + hi * 4) = w;  // ds_write_b64, bank-floor
      }
      rs += __shfl_xor(rs, 16);
      rs += __shfl_xor(rs, 32);
      l_run[qt] += rs;
    }
    asm volatile("s_waitcnt lgkmcnt(0)" ::: "memory");  // P visible across lanes (same wave)

    // O^T += V^T * P : A[m=d][k=t] from Vl, B[k=t][n=q] from Pl
#pragma unroll
    for (int ks = 0; ks < 2; ++ks) {
      bf16x8 p0 = *(const bf16x8*)(Pl[wid][0] + lo * 72 + ks * 32 + hi * 8);
      bf16x8 p1 = *(const bf16x8*)(Pl[wid][1] + lo * 72 + ks * 32 + hi * 8);
#pragma unroll
      for (int dt = 0; dt < 4; ++dt) {
        int r = dt * 16 + lo;
        int c = (hi + 4 * ks) ^ (r & 7);
        bf16x8 va = *(const bf16x8*)(Vb + r * 64 + c * 8);
        acco[0][dt] = __builtin_amdgcn_mfma_f32_16x16x32_bf16(va, p0, acco[0][dt], 0, 0, 0);
        acco[1][dt] = __builtin_amdgcn_mfma_f32_16x16x32_bf16(va, p1, acco[1][dt], 0, 0, 0);
      }
    }
  }

  // epilogue: O[q][d] = acco^T / l ; d = dt*16 + hi*4 + rg, packed 8B stores
#pragma unroll
  for (int qt = 0; qt < 2; ++qt) {
    float inv = 1.f / l_run[qt];
    const size_t row = (size_t)(b * 2048 + qbase + qt * 16 + lo);
#pragma unroll
    for (int dt = 0; dt < 4; ++dt) {
      float o0 = acco[qt][dt][0] * inv, o1 = acco[qt][dt][1] * inv;
      float o2 = acco[qt][dt][2] * inv, o3 = acco[qt][dt][3] * inv;
      uint2 w; w.x = cvtpk(o0, o1); w.y = cvtpk(o2, o3);
      *(uint2*)(ao + row * 1024 + h * 64 + dt * 16 + hi * 4) = w;
    }
  }
}

// ---------------- launch ----------------
extern "C" void kernel_launch(void* const* d_in, const int* in_sizes, int n_in,
                              void* d_out, int out_size, void* d_ws, size_t ws_size,
                              hipStream_t stream) {
  const float* x  = (const float*)d_in[0];
  const float* Wq = (const float*)d_in[1];
  const float* bq = (const float*)d_in[2];
  const float* Wk = (const float*)d_in[3];
  const float* bk = (const float*)d_in[4];
  const float* Wv = (const float*)d_in[5];
  const float* bv = (const float*)d_in[6];
  const float* Wo = (const float*)d_in[7];
  const float* bo = (const float*)d_in[8];
  float* out = (float*)d_out;

  char* ws = (char*)d_ws;
  u16* xb   = (u16*)(ws);                        // 8 MB  x bf16 [4096][1024]
  u16* wqkt = (u16*)(ws + (8u << 20));           // 4 MB  [2048][1024]
  u16* wvt  = (u16*)(ws + (12u << 20));          // 2 MB  [1024][1024]
  u16* wot  = (u16*)(ws + (14u << 20));          // 2 MB  [1024][1024]
  u16* qk   = (u16*)(ws + (16u << 20));          // 16 MB [4096][2048]
  u16* vt   = (u16*)(ws + (32u << 20));          // 8 MB  [2*16*64][2048]
  u16* aob  = (u16*)(ws + (40u << 20));          // 8 MB  [4096][1024]   (48 MB total)

  k_cast_x<<<4096, 256, 0, stream>>>(x, xb);
  k_prep_w<<<1024, 256, 0, stream>>>(Wq, Wk, Wv, Wo, wqkt, wvt, wot);
  k_gemm<0><<<dim3(16, 32), 256, 0, stream>>>(xb, wqkt, bq, bk, qk, nullptr);
  k_gemm<1><<<dim3(32, 8), 256, 0, stream>>>(wvt, xb, bv, nullptr, vt, nullptr);
  k_attn<<<512, 256, 0, stream>>>(qk, vt, aob);
  k_gemm<2><<<dim3(8, 32), 256, 0, stream>>>(aob, wot, bo, nullptr, nullptr, out);
}

// Round 3
// 135.496 us; speedup vs baseline: 1.5141x; 1.0892x over previous
//
#include <hip/hip_runtime.h>
#include <hip/hip_bf16.h>

#define DEV __device__ __forceinline__

typedef unsigned short u16;
typedef __attribute__((ext_vector_type(8))) short bf16x8;
typedef __attribute__((ext_vector_type(4))) float f32x4;
typedef __attribute__((ext_vector_type(16))) float f32x16;
typedef __attribute__((ext_vector_type(4))) unsigned short us4;
typedef __attribute__((ext_vector_type(2))) unsigned u32x2;

DEV void gld_lds16(const void* g, void* l) {
  __builtin_amdgcn_global_load_lds((const __attribute__((address_space(1))) void*)g,
                                   (__attribute__((address_space(3))) void*)l, 16, 0, 0);
}

DEV u16 f2bf(float x) {  // RNE f32->bf16 (inputs finite)
  union { float f; unsigned u; } v; v.f = x;
  unsigned r = v.u + 0x7FFFu + ((v.u >> 16) & 1u);
  return (u16)(r >> 16);
}

DEV float ex2(float x) {  // 2^x
  float r; asm("v_exp_f32 %0, %1" : "=v"(r) : "v"(x)); return r;
}

DEV unsigned cvtpk(float a, float b) {  // [bf16(b)<<16 | bf16(a)]
  unsigned r; asm("v_cvt_pk_bf16_f32 %0, %1, %2" : "=v"(r) : "v"(a), "v"(b)); return r;
}

// ---------------- prep: cast x to bf16 ----------------
__global__ __launch_bounds__(256) void k_cast_x(const float* __restrict__ x, u16* __restrict__ xb) {
  int i = (blockIdx.x * 256 + threadIdx.x) * 4;
  const float4 v = *(const float4*)(x + i);
  us4 o; o.x = f2bf(v.x); o.y = f2bf(v.y); o.z = f2bf(v.z); o.w = f2bf(v.w);
  *(us4*)(xb + i) = o;
}

// ---------------- prep: transpose-pack weights to bf16 ----------------
__global__ __launch_bounds__(256) void k_prep_w(const float* __restrict__ Wq, const float* __restrict__ Wk,
                                                const float* __restrict__ Wv, const float* __restrict__ Wo,
                                                u16* __restrict__ wqkt, u16* __restrict__ wvt,
                                                u16* __restrict__ wot) {
  __shared__ float t[64][65];
  const int bb = blockIdx.x, tid = threadIdx.x;
  const float* src; u16* dst; int src_ld, dst_row0, dst_col0;
  if (bb < 768) {
    int which = bb >> 8, h = (bb >> 4) & 15, m0 = (bb & 15) * 64;
    const float* W = which == 0 ? Wq : (which == 1 ? Wk : Wv);
    src = W + h * 65536 + m0 * 64; src_ld = 64;
    dst = (which == 2) ? wvt : (wqkt + (which == 1 ? (1024 * 1024) : 0));
    dst_row0 = h * 64; dst_col0 = m0;
  } else {
    int t2 = bb - 768, mt = t2 >> 4, nt = t2 & 15;
    src = Wo + (size_t)(mt * 64) * 1024 + nt * 64; src_ld = 1024;
    dst = wot; dst_row0 = nt * 64; dst_col0 = mt * 64;
  }
  {
    int r = tid >> 2, c0 = (tid & 3) * 16;
    const float* s = src + (size_t)r * src_ld + c0;
#pragma unroll
    for (int q = 0; q < 4; ++q) {
      float4 v = *(const float4*)(s + q * 4);
      t[r][c0 + q * 4 + 0] = v.x; t[r][c0 + q * 4 + 1] = v.y;
      t[r][c0 + q * 4 + 2] = v.z; t[r][c0 + q * 4 + 3] = v.w;
    }
  }
  __syncthreads();
  {
    int d = tid >> 2, mb = (tid & 3) * 16;
    bf16x8 v0, v1;
#pragma unroll
    for (int e = 0; e < 8; ++e) {
      v0[e] = (short)f2bf(t[mb + e][d]);
      v1[e] = (short)f2bf(t[mb + 8 + e][d]);
    }
    u16* dp = dst + (size_t)(dst_row0 + d) * 1024 + dst_col0 + mb;
    *(bf16x8*)(dp) = v0;
    *(bf16x8*)(dp + 8) = v1;
  }
}

// ---------------- GEMM: C[M,N] = A[M,K] x Bt[N,K]^T (+bias, epilogue by MODE) ----------------
// MODE 0: out bf16 qk[4096,2048]; Q cols scaled by 0.125*log2(e) (exp2-domain softmax)
// MODE 1: out bf16 vt[(b*16+h)*64+d][2048]
// MODE 2: out f32 d_out[4096,1024]
template <int MODE>
__global__ __launch_bounds__(256) void k_gemm(const u16* __restrict__ A, const u16* __restrict__ Bt,
                                              const float* __restrict__ b0, const float* __restrict__ b1,
                                              u16* __restrict__ outb, float* __restrict__ outf) {
  constexpr int K = 1024;
  __shared__ __align__(16) u16 As[128 * 64];
  __shared__ __align__(16) u16 Bs[128 * 64];
  const int tid = threadIdx.x, wid = tid >> 6, lane = tid & 63;
  const int lo = lane & 15, hi = lane >> 4;
  const int wr = wid >> 1, wc = wid & 1;
  const int bm = blockIdx.y, bn = blockIdx.x;
  const u16* Ab = A + (size_t)bm * 128 * K;
  const u16* Bb = Bt + (size_t)bn * 128 * K;
  const int sr = lane >> 3, sc = lane & 7;
  f32x4 acc[4][4] = {};
  for (int k0 = 0; k0 < K; k0 += 64) {
    __syncthreads();
#pragma unroll
    for (int i = 0; i < 4; ++i) {
      int r = wid * 32 + i * 8 + sr;
      int cs = sc ^ (r & 7);
      gld_lds16(Ab + (size_t)r * K + k0 + cs * 8, As + (wid * 32 + i * 8) * 64);
      gld_lds16(Bb + (size_t)r * K + k0 + cs * 8, Bs + (wid * 32 + i * 8) * 64);
    }
    __syncthreads();
#pragma unroll
    for (int ks = 0; ks < 2; ++ks) {
      bf16x8 af[4], bfr[4];
#pragma unroll
      for (int mt = 0; mt < 4; ++mt) {
        int r = wr * 64 + mt * 16 + lo;
        int c = (hi + 4 * ks) ^ (r & 7);
        af[mt] = *(const bf16x8*)(As + r * 64 + c * 8);
      }
#pragma unroll
      for (int nt = 0; nt < 4; ++nt) {
        int r = wc * 64 + nt * 16 + lo;
        int c = (hi + 4 * ks) ^ (r & 7);
        bfr[nt] = *(const bf16x8*)(Bs + r * 64 + c * 8);
      }
#pragma unroll
      for (int mt = 0; mt < 4; ++mt)
#pragma unroll
        for (int nt = 0; nt < 4; ++nt)
          acc[mt][nt] = __builtin_amdgcn_mfma_f32_16x16x32_bf16(af[mt], bfr[nt], acc[mt][nt], 0, 0, 0);
    }
  }
#pragma unroll
  for (int mt = 0; mt < 4; ++mt) {
#pragma unroll
    for (int nt = 0; nt < 4; ++nt) {
      const int i0 = bm * 128 + wr * 64 + mt * 16 + hi * 4;
      const int j = bn * 128 + wc * 64 + nt * 16 + lo;
#pragma unroll
      for (int rg = 0; rg < 4; ++rg) {
        const int i = i0 + rg;
        float v = acc[mt][nt][rg];
        if (MODE == 0) {
          v += (j < 1024) ? b0[j] : b1[j - 1024];
          if (j < 1024) v *= 0.18033688011112042f;  // (1/8)*log2(e): exp2-domain logits
          outb[(size_t)i * 2048 + j] = f2bf(v);
        } else if (MODE == 1) {
          v += b0[i];
          outb[(size_t)((j >> 11) * 1024 + i) * 2048 + (j & 2047)] = f2bf(v);
        } else {
          v += b0[j];
          outf[(size_t)i * 1024 + j] = v;
        }
      }
    }
  }
}

// ---------------- flash attention (32x32 MFMA, P fully in-register) ----------------
// qk: [4096][2048] bf16 (Q cols pre-scaled by (1/8)log2e, K cols 1024..2047)
// vt: [(b*16+h)*64 + d][2048] bf16 (V transposed)
// ao: [4096][1024] bf16 concat output
// Block: 4 waves x 32 q = 128 q. Wave computes S^T = mfma32(K, Q): lane owns
// q = lane&31 (row split across lane pair lane^32). Softmax lane-local: l-sum
// deferred to end (1 shuffle total), max via defer-THR + __any ballot (shuffles
// only on rare rescale). P -> PV B-frags via cvt_pk + 2 permlane32_swap per
// k-step: zero LDS traffic for P.
__global__ __launch_bounds__(256, 2) void k_attn(const u16* __restrict__ qk, const u16* __restrict__ vt,
                                                 u16* __restrict__ ao) {
  __shared__ __align__(16) u16 Kl[2][64 * 64];
  __shared__ __align__(16) u16 Vl[2][64 * 64];
  const int tid = threadIdx.x, wid = tid >> 6, lane = tid & 63;
  const int ql = lane & 31, Lh = lane >> 5;
  const int qb = blockIdx.x & 15, bh = blockIdx.x >> 4;
  const int b = bh >> 4, h = bh & 15;
  const int qg = qb * 128 + wid * 32 + ql;  // q within this batch's sequence

  // Q as B-frags (lane: n=q=ql, k=d=Lh*8+e per 16-k step), kd=0..3
  bf16x8 qB[4];
  const u16* qrow = qk + (size_t)(b * 2048 + qg) * 2048 + h * 64;
#pragma unroll
  for (int kd = 0; kd < 4; ++kd) qB[kd] = *(const bf16x8*)(qrow + kd * 16 + Lh * 8);

  const u16* Kg = qk + 1024 + (size_t)b * 2048 * 2048 + h * 64;  // + t*2048
  const u16* Vg = vt + (size_t)bh * 64 * 2048;                   // + d*2048 + t
  const int sr = lane >> 3, sc = lane & 7;

  f32x16 acco[2] = {};
  float m_run = -1e30f, l_part = 0.f;

  // stage tile 0
#pragma unroll
  for (int i = 0; i < 2; ++i) {
    int r = wid * 16 + i * 8 + sr;
    int cs = sc ^ (r & 7);
    gld_lds16(Kg + (size_t)r * 2048 + cs * 8, Kl[0] + (wid * 16 + i * 8) * 64);
    gld_lds16(Vg + (size_t)r * 2048 + cs * 8, Vl[0] + (wid * 16 + i * 8) * 64);
  }

  for (int it = 0; it < 32; ++it) {
    __syncthreads();  // tile `it` staged (vmcnt(0) drained at barrier)
    if (it + 1 < 32) {
      const int t0 = (it + 1) * 64, bufn = (it + 1) & 1;
#pragma unroll
      for (int i = 0; i < 2; ++i) {
        int r = wid * 16 + i * 8 + sr;
        int cs = sc ^ (r & 7);
        gld_lds16(Kg + (size_t)(t0 + r) * 2048 + cs * 8, Kl[bufn] + (wid * 16 + i * 8) * 64);
        gld_lds16(Vg + (size_t)r * 2048 + t0 + cs * 8, Vl[bufn] + (wid * 16 + i * 8) * 64);
      }
    }
    const u16* Kb = Kl[it & 1];
    const u16* Vb = Vl[it & 1];

    // S^T = K * Q : C[m=t][n=q]; lane holds 16 t-values per 32-t tile for q=ql
    f32x16 accs[2] = {};
#pragma unroll
    for (int kd = 0; kd < 4; ++kd) {
      int cg = 2 * kd + Lh;  // 8-elem col-group in d
#pragma unroll
      for (int tt = 0; tt < 2; ++tt) {
        int r = tt * 32 + ql;
        bf16x8 ka = *(const bf16x8*)(Kb + r * 64 + (cg ^ (r & 7)) * 8);
        accs[tt] = __builtin_amdgcn_mfma_f32_32x32x16_bf16(ka, qB[kd], accs[tt], 0, 0, 0);
      }
    }

    // V A-frags loaded early: DS latency hides under softmax VALU
    bf16x8 vf[2][4];
#pragma unroll
    for (int dt = 0; dt < 2; ++dt)
#pragma unroll
      for (int kt = 0; kt < 4; ++kt) {
        int r = dt * 32 + ql;
        int cg = 2 * kt + Lh;
        vf[dt][kt] = *(const bf16x8*)(Vb + r * 64 + (cg ^ (r & 7)) * 8);
      }

    // lane-local max tree (depth ~5)
    float t8[8];
#pragma unroll
    for (int m = 0; m < 8; ++m)
      t8[m] = fmaxf(fmaxf(accs[0][2 * m], accs[0][2 * m + 1]),
                    fmaxf(accs[1][2 * m], accs[1][2 * m + 1]));
    float mx = fmaxf(fmaxf(fmaxf(t8[0], t8[1]), fmaxf(t8[2], t8[3])),
                     fmaxf(fmaxf(t8[4], t8[5]), fmaxf(t8[6], t8[7])));

    if (__any(mx > m_run + 8.f)) {  // rare after warm-up: defer-max
      float mxw = fmaxf(mx, __shfl_xor(mx, 32));
      float mnew = fmaxf(m_run, mxw);
      float al = ex2(m_run - mnew);
      m_run = mnew;
      l_part *= al;
      acco[0] *= al;
      acco[1] *= al;
    }

    // exp2 + pack P pairs; l accumulates lane-locally (combined once at end)
    unsigned dw[2][8];
    float ls0 = 0.f, ls1 = 0.f;
#pragma unroll
    for (int tt = 0; tt < 2; ++tt)
#pragma unroll
      for (int m = 0; m < 8; ++m) {
        float p0 = ex2(accs[tt][2 * m] - m_run);
        float p1 = ex2(accs[tt][2 * m + 1] - m_run);
        if (m & 1) ls1 += p0 + p1; else ls0 += p0 + p1;
        dw[tt][m] = cvtpk(p0, p1);
      }
    l_part += ls0 + ls1;

    // O^T += V^T * P : per k-step, B-frag from 2 permlane32_swap
#pragma unroll
    for (int kt = 0; kt < 4; ++kt) {
      const int tt = kt >> 1, c = kt & 1;
      u32x2 s0 = __builtin_amdgcn_permlane32_swap(dw[tt][4 * c + 0], dw[tt][4 * c + 2], false, false);
      u32x2 s1 = __builtin_amdgcn_permlane32_swap(dw[tt][4 * c + 1], dw[tt][4 * c + 3], false, false);
      union { unsigned u[4]; bf16x8 v; } pb;
      pb.u[0] = s0[0]; pb.u[1] = s1[0]; pb.u[2] = s0[1]; pb.u[3] = s1[1];
#pragma unroll
      for (int dt = 0; dt < 2; ++dt)
        acco[dt] = __builtin_amdgcn_mfma_f32_32x32x16_bf16(vf[dt][kt], pb.v, acco[dt], 0, 0, 0);
    }
  }

  // epilogue: O[q][d], d = 32dt + 8g + 4Lh + (reg&3)
  float lsum = l_part + __shfl_xor(l_part, 32);
  float inv = 1.f / lsum;
  u16* orow = ao + (size_t)(b * 2048 + qg) * 1024 + h * 64;
#pragma unroll
  for (int dt = 0; dt < 2; ++dt)
#pragma unroll
    for (int g = 0; g < 4; ++g) {
      float o0 = acco[dt][4 * g + 0] * inv, o1 = acco[dt][4 * g + 1] * inv;
      float o2 = acco[dt][4 * g + 2] * inv, o3 = acco[dt][4 * g + 3] * inv;
      uint2 w; w.x = cvtpk(o0, o1); w.y = cvtpk(o2, o3);
      *(uint2*)(orow + dt * 32 + g * 8 + Lh * 4) = w;
    }
}

// ---------------- launch ----------------
extern "C" void kernel_launch(void* const* d_in, const int* in_sizes, int n_in,
                              void* d_out, int out_size, void* d_ws, size_t ws_size,
                              hipStream_t stream) {
  const float* x  = (const float*)d_in[0];
  const float* Wq = (const float*)d_in[1];
  const float* bq = (const float*)d_in[2];
  const float* Wk = (const float*)d_in[3];
  const float* bk = (const float*)d_in[4];
  const float* Wv = (const float*)d_in[5];
  const float* bv = (const float*)d_in[6];
  const float* Wo = (const float*)d_in[7];
  const float* bo = (const float*)d_in[8];
  float* out = (float*)d_out;

  char* ws = (char*)d_ws;
  u16* xb   = (u16*)(ws);                        // 8 MB  x bf16 [4096][1024]
  u16* wqkt = (u16*)(ws + (8u << 20));           // 4 MB  [2048][1024]
  u16* wvt  = (u16*)(ws + (12u << 20));          // 2 MB  [1024][1024]
  u16* wot  = (u16*)(ws + (14u << 20));          // 2 MB  [1024][1024]
  u16* qk   = (u16*)(ws + (16u << 20));          // 16 MB [4096][2048]
  u16* vt   = (u16*)(ws + (32u << 20));          // 8 MB  [2*16*64][2048]
  u16* aob  = (u16*)(ws + (40u << 20));          // 8 MB  [4096][1024]   (48 MB total)

  k_cast_x<<<4096, 256, 0, stream>>>(x, xb);
  k_prep_w<<<1024, 256, 0, stream>>>(Wq, Wk, Wv, Wo, wqkt, wvt, wot);
  k_gemm<0><<<dim3(16, 32), 256, 0, stream>>>(xb, wqkt, bq, bk, qk, nullptr);
  k_gemm<1><<<dim3(32, 8), 256, 0, stream>>>(wvt, xb, bv, nullptr, vt, nullptr);
  k_attn<<<512, 256, 0, stream>>>(qk, vt, aob);
  k_gemm<2><<<dim3(8, 32), 256, 0, stream>>>(aob, wot, bo, nullptr, nullptr, out);
}